// Round 5
// baseline (323.510 us; speedup 1.0000x reference)
//
#include <hip/hip_runtime.h>

// Problem constants (fixed by reference setup_inputs)
#define NB 8
#define NA 3
#define NH 160
#define NW 160
#define NCLS 80
#define NGT 32
#define NPB (NA * NH * NW)        // 76,800 cells per batch
#define TOTAL (NB * NPB)          // 614,400 cells
#define NBLK (TOTAL / 256)        // 2400 blocks
// Output: ONE flat float32 buffer, outputs concatenated in return order:
// p_bbox [8,76800,4] | cls_idx [8,76800] | score [8,76800] | loss [1]
#define OFF_CLSIDX (TOTAL * 4)    // 2,457,600  (f32 elements)
#define OFF_SCORE  (TOTAL * 5)    // 3,072,000
#define OFF_LOSS   (TOTAL * 6)    // 3,686,400

#define F4_PER_ROW 20             // 80 classes = 20 float4 per cell

// Loss accumulator owned by this .so.
// INVARIANT: 0 on kernel entry. det_fin_k (same graph, after det_all_k)
// reads it and resets it, so every graph replay sees clean state.
// NO device fences (round-1 lesson: per-block __threadfence on multi-XCD
// gfx950 cost ~90 us across 2400 blocks). Kernel boundary = coherence.
__device__ float g_acc = 0.0f;

__device__ __forceinline__ float det_sigmoid(float x) { return 1.0f / (1.0f + expf(-x)); }
__device__ __forceinline__ float det_bce(float x, float t) {
    return fmaxf(x, 0.0f) - x * t + log1pf(expf(-fabsf(x)));
}
__device__ __forceinline__ float det_aw3(int a) { return a == 0 ? 10.0f : (a == 1 ? 16.0f : 33.0f); }
__device__ __forceinline__ float det_ah3(int a) { return a == 0 ? 13.0f : (a == 1 ? 30.0f : 23.0f); }

// gt_mask layout detection (u8 bool vs int32), deterministic each call.
__device__ __forceinline__ bool det_mask_is_u8(const void* p) {
    const unsigned int* w = (const unsigned int*)p;
    unsigned int acc = 0;
#pragma unroll
    for (int k = 0; k < 64; k++) acc |= (w[k] & 0xFFFFFF00u);
    return acc != 0;
}
__device__ __forceinline__ bool det_mask_at(const void* p, bool u8mode, int idx) {
    return u8mode ? (((const unsigned char*)p)[idx] != 0)
                  : (((const int*)p)[idx] != 0);
}

// Per-(b,g) target losses (xy, wh, cls) — one thread each (256 = 8*32).
// Block 0 only; returns 0 for invalid GTs so it folds into the conf-loss
// wave reduction. (Verified correct in rounds 1-4.)
__device__ __forceinline__ float det_gt_loss(int tid,
        const float* __restrict__ t_bbox,
        const float* __restrict__ cls_logits,
        const float* __restrict__ gt_bboxes,
        const int* __restrict__ gt_cls,
        const void* __restrict__ gt_mask) {
    bool u8mode = det_mask_is_u8(gt_mask);
    int b = tid >> 5;
    int g = tid & 31;
    float4 gtb = ((const float4*)gt_bboxes)[b * NGT + g];
    float cx = gtb.x, cy = gtb.y, gw = gtb.z, gh = gtb.w;

    const float aw9[9] = {10.f,16.f,33.f,30.f,62.f,59.f,116.f,156.f,373.f};
    const float ah9[9] = {13.f,30.f,23.f,61.f,45.f,119.f,90.f,198.f,326.f};
    float garea = gw * gh;
    int aidx = 0;
    float best = -1.0f;
#pragma unroll
    for (int k = 0; k < 9; k++) {
        float inter = fminf(gw, aw9[k]) * fminf(gh, ah9[k]);
        float uni = garea + aw9[k] * ah9[k] - inter;
        float r = inter / (uni + 1e-16f);
        if (r > best) { best = r; aidx = k; }
    }
    bool valid = det_mask_at(gt_mask, u8mode, b * NGT + g) && (aidx < NA);
    int ta = aidx % NA;
    int ti = min(max((int)(cx * 0.125f), 0), NW - 1);
    int tj = min(max((int)(cy * 0.125f), 0), NH - 1);
    size_t cell = ((size_t)(b * NA + ta) * NH + tj) * NW + ti;

    float4 tb = ((const float4*)t_bbox)[cell];
    float fx = cx * 0.125f; fx -= floorf(fx);
    float fy = cy * 0.125f; fy -= floorf(fy);
    float tx = (fx + 0.5f) * 0.5f;
    float ty = (fy + 0.5f) * 0.5f;
    float tw = sqrtf(gw / det_aw3(ta)) * 0.5f;
    float th = sqrtf(gh / det_ah3(ta)) * 0.5f;

    float l = det_bce(tb.x, tx) + det_bce(tb.y, ty) +
              det_bce(tb.z, tw) + det_bce(tb.w, th);

    const float4* cl = (const float4*)(cls_logits + cell * NCLS);
    int tc = gt_cls[b * NGT + g];
    float lc = 0.0f;
#pragma unroll
    for (int c4 = 0; c4 < NCLS / 4; c4++) {
        float4 v = cl[c4];
        int c = c4 * 4;
        lc += det_bce(v.x, (c + 0 == tc) ? 1.0f : 0.0f);
        lc += det_bce(v.y, (c + 1 == tc) ? 1.0f : 0.0f);
        lc += det_bce(v.z, (c + 2 == tc) ? 1.0f : 0.0f);
        lc += det_bce(v.w, (c + 3 == tc) ? 1.0f : 0.0f);
    }
    l += lc * (1.0f / NCLS);
    return valid ? l : 0.0f;
}

// ---------------- Main fused kernel ----------------------------------------
// Block = 256 threads (4 waves) = 256 cells; NPB % 256 == 0.
// ROUND-5 CHANGE — direct-from-global class scan, NO LDS staging:
//   Round-3 (GLDS double-buffer, 12 waves/CU) beat round-4 (single-buffer,
//   28 waves/CU): schedule quality > occupancy. This round takes both:
//   quad mapping (4 lanes/cell, lane l reads bytes wavebase + 80*l + 16*k)
//   is LINEAR IN LANE at stride 80B — each instruction touches 80 cache
//   lines but the 5 instructions of a tile consume every line fully, so
//   HBM traffic is unchanged; only L1 tag work rises (~4x, parallel).
//   In exchange: no DMA, no waitcnt choreography, no LDS hazards, LDS
//   20 KB -> 0.8 KB, occupancy VGPR-bound (launch_bounds(256,6) -> 24
//   waves/CU), and with zero barriers between phase-1 tail and the
//   epilogue the compiler freely hoists tile loads across the IoU loop
//   and across tiles (ILP) while TLP covers the rest.
__global__ __launch_bounds__(256, 6) void det_all_k(
    const float* __restrict__ t_bbox,
    const float* __restrict__ conf_logits,
    const float* __restrict__ cls_logits,
    const float* __restrict__ gt_bboxes,
    const int* __restrict__ gt_cls,
    const void* __restrict__ gt_mask,
    float* __restrict__ out) {
    __shared__ float4 s_box[NGT];                  // x1,y1,x2,y2
    __shared__ float2 s_am[NGT];                   // area, mask
    __shared__ float s_part[4];

    int tid = threadIdx.x;
    int blockCell = blockIdx.x * 256;
    int gid = blockCell + tid;
    int b = gid / NPB;          // uniform within a block
    int r = gid % NPB;

    if (tid < NGT) {
        bool u8mode = det_mask_is_u8(gt_mask);
        float4 gtb = ((const float4*)gt_bboxes)[b * NGT + tid];
        float4 bx;
        bx.x = gtb.x - gtb.z * 0.5f;   // x1
        bx.y = gtb.y - gtb.w * 0.5f;   // y1
        bx.z = gtb.x + gtb.z * 0.5f;   // x2
        bx.w = gtb.y + gtb.w * 0.5f;   // y2
        s_box[tid] = bx;
        float2 am;
        am.x = gtb.z * gtb.w;
        am.y = det_mask_at(gt_mask, u8mode, b * NGT + tid) ? 1.0f : 0.0f;
        s_am[tid] = am;
    }
    __syncthreads();   // barrier #1 (of 2): GT tile staged

    // ---- Phase 1: bbox decode + IoU + conf BCE ----
    int a   = r / (NH * NW);
    int rem = r % (NH * NW);
    int j   = rem / NW;
    int i   = rem % NW;

    float4 tb = ((const float4*)t_bbox)[gid];
    float confl = conf_logits[gid];
    float s0 = det_sigmoid(tb.x), s1 = det_sigmoid(tb.y);
    float s2 = det_sigmoid(tb.z), s3 = det_sigmoid(tb.w);
    float px = (s0 * 2.0f - 0.5f + (float)i) * 8.0f;
    float py = (s1 * 2.0f - 0.5f + (float)j) * 8.0f;
    float sw = s2 * 2.0f, sh = s3 * 2.0f;
    float pw = sw * sw * det_aw3(a);
    float ph = sh * sh * det_ah3(a);
    float4 pb; pb.x = px; pb.y = py; pb.z = pw; pb.w = ph;
    ((float4*)out)[gid] = pb;

    float px1 = px - pw * 0.5f, px2 = px + pw * 0.5f;
    float py1 = py - ph * 0.5f, py2 = py + ph * 0.5f;
    float parea = pw * ph;
    float maxiou = 0.0f;
#pragma unroll
    for (int g = 0; g < NGT; g++) {
        float4 bx = s_box[g];
        float2 am = s_am[g];
        float iw = fmaxf(fminf(px2, bx.z) - fmaxf(px1, bx.x), 0.0f);
        float ih = fmaxf(fminf(py2, bx.w) - fmaxf(py1, bx.y), 0.0f);
        float inter = iw * ih;
        float uni = parea + am.x - inter;
        float iou = inter / (uni + 1e-16f);
        maxiou = fmaxf(maxiou, (am.y != 0.0f) ? iou : 0.0f);
    }

    float sconf = det_sigmoid(confl);          // kept for phase 2 via shuffle
    float lconf = det_bce(confl, maxiou);

    // Block 0 carries the GT target losses, folded into the reduce chain.
    if (blockIdx.x == 0)
        lconf += det_gt_loss(tid, t_bbox, cls_logits, gt_bboxes, gt_cls, gt_mask);

#pragma unroll
    for (int off = 32; off > 0; off >>= 1) lconf += __shfl_down(lconf, off, 64);
    int w = tid >> 6, l = tid & 63;
    if (l == 0) s_part[w] = lconf;   // consumed after the final barrier

    // ---- Phase 2: class argmax + score, direct global quad-mapped loads ----
    int cl_ = l >> 2;            // local cell within 16-row tile
    int q   = l & 3;             // quad lane: scans cols [5q, 5q+5)
    const float4* g4 = (const float4*)cls_logits;
    int wbase = blockCell + w * 64;            // first cell of this wave

#pragma unroll
    for (int it = 0; it < 4; ++it) {
        int tileCell = wbase + it * 16;
        // lane address = (tileCell)*320B + 80*l + 16*k  (linear in lane)
        const float4* rowp = g4 + (size_t)(tileCell + cl_) * F4_PER_ROW + q * 5;
        float4 v0 = rowp[0];
        float4 v1 = rowp[1];
        float4 v2 = rowp[2];
        float4 v3 = rowp[3];
        float4 v4 = rowp[4];

        float mx = -1e30f;
        int mi = 0;
        int cb = q * 20;                       // first class of this lane
        { int c = cb;
          if (v0.x > mx) { mx = v0.x; mi = c + 0; }
          if (v0.y > mx) { mx = v0.y; mi = c + 1; }
          if (v0.z > mx) { mx = v0.z; mi = c + 2; }
          if (v0.w > mx) { mx = v0.w; mi = c + 3; } }
        { int c = cb + 4;
          if (v1.x > mx) { mx = v1.x; mi = c + 0; }
          if (v1.y > mx) { mx = v1.y; mi = c + 1; }
          if (v1.z > mx) { mx = v1.z; mi = c + 2; }
          if (v1.w > mx) { mx = v1.w; mi = c + 3; } }
        { int c = cb + 8;
          if (v2.x > mx) { mx = v2.x; mi = c + 0; }
          if (v2.y > mx) { mx = v2.y; mi = c + 1; }
          if (v2.z > mx) { mx = v2.z; mi = c + 2; }
          if (v2.w > mx) { mx = v2.w; mi = c + 3; } }
        { int c = cb + 12;
          if (v3.x > mx) { mx = v3.x; mi = c + 0; }
          if (v3.y > mx) { mx = v3.y; mi = c + 1; }
          if (v3.z > mx) { mx = v3.z; mi = c + 2; }
          if (v3.w > mx) { mx = v3.w; mi = c + 3; } }
        { int c = cb + 16;
          if (v4.x > mx) { mx = v4.x; mi = c + 0; }
          if (v4.y > mx) { mx = v4.y; mi = c + 1; }
          if (v4.z > mx) { mx = v4.z; mi = c + 2; }
          if (v4.w > mx) { mx = v4.w; mi = c + 3; } }

        // quad reduce: lexicographic (value, lower index) == jnp first-max
#pragma unroll
        for (int s = 1; s < 4; s <<= 1) {
            float ov = __shfl_xor(mx, s, 64);
            int   oi = __shfl_xor(mi, s, 64);
            if (ov > mx || (ov == mx && oi < mi)) { mx = ov; mi = oi; }
        }
        // sigmoid(conf) of this tile's cell lives in lane it*16+cl_ (phase 1)
        float sc = __shfl(sconf, it * 16 + cl_, 64);
        if (q == 0) {                          // 16 lanes, 64B contiguous
            int cellg = tileCell + cl_;
            out[OFF_CLSIDX + cellg] = (float)mi;
            out[OFF_SCORE  + cellg] = sc * det_sigmoid(mx);
        }
    }

    // ---- Epilogue: block partial -> device atomic --------------------------
    __syncthreads();   // barrier #2 (of 2): s_part ready
    if (tid == 0)
        atomicAdd(&g_acc, s_part[0] + s_part[1] + s_part[2] + s_part[3]);
}

// ---------------- Finalize: write loss, reset accumulator ------------------
__global__ void det_fin_k(float* __restrict__ out) {
    out[OFF_LOSS] = g_acc * (1.0f / NB);
    g_acc = 0.0f;
}

extern "C" void kernel_launch(void* const* d_in, const int* in_sizes, int n_in,
                              void* d_out, int out_size, void* d_ws, size_t ws_size,
                              hipStream_t stream) {
    (void)in_sizes; (void)n_in; (void)out_size; (void)d_ws; (void)ws_size;
    const float* t_bbox      = (const float*)d_in[0];
    const float* conf_logits = (const float*)d_in[1];
    const float* cls_logits  = (const float*)d_in[2];
    const float* gt_bboxes   = (const float*)d_in[3];
    const int*   gt_cls      = (const int*)d_in[4];
    const void*  gt_mask     = (const void*)d_in[5];  // layout auto-detected
    float* out = (float*)d_out;                       // float32 per reference

    det_all_k<<<NBLK, 256, 0, stream>>>(t_bbox, conf_logits, cls_logits,
                                        gt_bboxes, gt_cls, gt_mask, out);
    det_fin_k<<<1, 1, 0, stream>>>(out);
}

// Round 6
// 299.532 us; speedup vs baseline: 1.0800x; 1.0800x over previous
//
#include <hip/hip_runtime.h>

// Problem constants (fixed by reference setup_inputs)
#define NB 8
#define NA 3
#define NH 160
#define NW 160
#define NCLS 80
#define NGT 32
#define NPB (NA * NH * NW)        // 76,800 cells per batch
#define TOTAL (NB * NPB)          // 614,400 cells
#define BLK 64                    // ONE wave per block (round-6 change)
#define NBLK (TOTAL / BLK)        // 9600 blocks; NPB % 64 == 0
// Output: ONE flat float32 buffer, outputs concatenated in return order:
// p_bbox [8,76800,4] | cls_idx [8,76800] | score [8,76800] | loss [1]
#define OFF_CLSIDX (TOTAL * 4)    // 2,457,600  (f32 elements)
#define OFF_SCORE  (TOTAL * 5)    // 3,072,000
#define OFF_LOSS   (TOTAL * 6)    // 3,686,400

#define F4_PER_ROW 20             // 80 classes = 20 float4 per cell

// Loss accumulator slots, 64B-spaced to avoid same-line atomic contention
// (9600 blocks now vs 2400 before). INVARIANT: all-zero on kernel entry;
// det_fin_k sums and re-zeros them each replay. NO device fences anywhere
// (round-1 lesson: ~90 us). Kernel boundary = coherence.
__device__ float g_acc[8 * 16];   // slot s at [s*16]

__device__ __forceinline__ float det_rcp(float x) {
    return __builtin_amdgcn_rcpf(x);   // ~1e-6 rel err; continuous paths only
}
__device__ __forceinline__ float det_sigmoid(float x) {
    return det_rcp(1.0f + expf(-x));   // expf(inf)->inf, rcp(inf)=0: safe
}
__device__ __forceinline__ float det_bce(float x, float t) {
    return fmaxf(x, 0.0f) - x * t + log1pf(expf(-fabsf(x)));
}
__device__ __forceinline__ float det_aw3(int a) { return a == 0 ? 10.0f : (a == 1 ? 16.0f : 33.0f); }
__device__ __forceinline__ float det_ah3(int a) { return a == 0 ? 13.0f : (a == 1 ? 30.0f : 23.0f); }

// gt_mask layout detection (u8 bool vs int32), deterministic each call.
__device__ __forceinline__ bool det_mask_is_u8(const void* p) {
    const unsigned int* w = (const unsigned int*)p;
    unsigned int acc = 0;
#pragma unroll
    for (int k = 0; k < 64; k++) acc |= (w[k] & 0xFFFFFF00u);
    return acc != 0;
}
__device__ __forceinline__ bool det_mask_at(const void* p, bool u8mode, int idx) {
    return u8mode ? (((const unsigned char*)p)[idx] != 0)
                  : (((const int*)p)[idx] != 0);
}

// Per-(b,g) target losses (xy, wh, cls) — one (b,g) pair per thread.
// Blocks 0..3 cover tid = blockIdx.x*64 + lane in [0,256) = 8 batches x 32.
// EXACT division kept here: anchor argmax is discrete (a flipped match
// would move the target cell) — not worth the rcp risk for 256 threads.
__device__ __forceinline__ float det_gt_loss(int tid,
        const float* __restrict__ t_bbox,
        const float* __restrict__ cls_logits,
        const float* __restrict__ gt_bboxes,
        const int* __restrict__ gt_cls,
        const void* __restrict__ gt_mask) {
    bool u8mode = det_mask_is_u8(gt_mask);
    int b = tid >> 5;
    int g = tid & 31;
    float4 gtb = ((const float4*)gt_bboxes)[b * NGT + g];
    float cx = gtb.x, cy = gtb.y, gw = gtb.z, gh = gtb.w;

    const float aw9[9] = {10.f,16.f,33.f,30.f,62.f,59.f,116.f,156.f,373.f};
    const float ah9[9] = {13.f,30.f,23.f,61.f,45.f,119.f,90.f,198.f,326.f};
    float garea = gw * gh;
    int aidx = 0;
    float best = -1.0f;
#pragma unroll
    for (int k = 0; k < 9; k++) {
        float inter = fminf(gw, aw9[k]) * fminf(gh, ah9[k]);
        float uni = garea + aw9[k] * ah9[k] - inter;
        float r = inter / (uni + 1e-16f);      // exact: discrete argmax
        if (r > best) { best = r; aidx = k; }
    }
    bool valid = det_mask_at(gt_mask, u8mode, b * NGT + g) && (aidx < NA);
    int ta = aidx % NA;
    int ti = min(max((int)(cx * 0.125f), 0), NW - 1);
    int tj = min(max((int)(cy * 0.125f), 0), NH - 1);
    size_t cell = ((size_t)(b * NA + ta) * NH + tj) * NW + ti;

    float4 tb = ((const float4*)t_bbox)[cell];
    float fx = cx * 0.125f; fx -= floorf(fx);
    float fy = cy * 0.125f; fy -= floorf(fy);
    float tx = (fx + 0.5f) * 0.5f;
    float ty = (fy + 0.5f) * 0.5f;
    float tw = sqrtf(gw / det_aw3(ta)) * 0.5f;
    float th = sqrtf(gh / det_ah3(ta)) * 0.5f;

    float l = det_bce(tb.x, tx) + det_bce(tb.y, ty) +
              det_bce(tb.z, tw) + det_bce(tb.w, th);

    const float4* cl = (const float4*)(cls_logits + cell * NCLS);
    int tc = gt_cls[b * NGT + g];
    float lc = 0.0f;
#pragma unroll
    for (int c4 = 0; c4 < NCLS / 4; c4++) {
        float4 v = cl[c4];
        int c = c4 * 4;
        lc += det_bce(v.x, (c + 0 == tc) ? 1.0f : 0.0f);
        lc += det_bce(v.y, (c + 1 == tc) ? 1.0f : 0.0f);
        lc += det_bce(v.z, (c + 2 == tc) ? 1.0f : 0.0f);
        lc += det_bce(v.w, (c + 3 == tc) ? 1.0f : 0.0f);
    }
    l += lc * (1.0f / NCLS);
    return valid ? l : 0.0f;
}

// Issue one 16-row class tile (320 consecutive float4) as 5 direct
// global->LDS DMA loads (width 16B). No VGPR staging => no spill possible
// (round-2 lesson: reg-staged tiles spilled, +133 MB scratch writes).
// Round-5 lesson: direct (uncoalesced) global scan is 4-5x worse — LDS
// staging via coalesced DMA is mandatory.
__device__ __forceinline__ void det_issue_tile(const float4* g4, float4* ldsbase,
                                               size_t f4base, int l) {
#pragma unroll
    for (int k = 0; k < 5; ++k) {
        __builtin_amdgcn_global_load_lds(
            (const __attribute__((address_space(1))) void*)(g4 + f4base + k * 64 + l),
            (__attribute__((address_space(3))) void*)(ldsbase + k * 64),
            16, 0, 0);
    }
}

// Counted vmcnt wait + sched fence (rule #18: compiler may hoist ops past
// an inline-asm waitcnt; the fence pins the following DS reads).
// vmcnt retires in order (m135): vmcnt(N) => all but the newest N VMEM ops
// are done — interleaved stores/extra loads only make waits conservative.
#define DET_WAITVM(N) do { \
    asm volatile("s_waitcnt vmcnt(" #N ")" ::: "memory"); \
    __builtin_amdgcn_sched_barrier(0); \
} while (0)

// ---------------- Main fused kernel ----------------------------------------
// ROUND-6: ONE WAVE PER BLOCK (64 threads), round-3's proven double-buffer
// GLDS pipeline kept verbatim. Why: r3 (dbuf, 12 waves/CU) beat r4 (single
// buffer, 28 waves/CU) and r5 (no LDS) — schedule quality first, THEN
// occupancy. 1-wave blocks keep the schedule and:
//   * LDS 41.7 KB -> ~11 KB  => 14 blocks/CU = 14 waves/CU (was 12)
//   * zero __syncthreads (GT staging + tiles are same-wave in-order DS)
//   * no s_part stage: shuffle-reduce -> lane-0 atomic (8 spread slots)
// Fast-rcp (1e-6) replaces IEEE div in continuous paths (sigmoid, IoU max).
__global__ __launch_bounds__(64, 4) void det_all_k(
    const float* __restrict__ t_bbox,
    const float* __restrict__ conf_logits,
    const float* __restrict__ cls_logits,
    const float* __restrict__ gt_bboxes,
    const int* __restrict__ gt_cls,
    const void* __restrict__ gt_mask,
    float* __restrict__ out) {
    __shared__ float4 s_cls[2][16 * F4_PER_ROW];   // 10 KB: 2 tile buffers
    __shared__ float4 s_box[NGT];                  // x1,y1,x2,y2
    __shared__ float2 s_am[NGT];                   // area, mask

    int l = threadIdx.x;                 // lane 0..63 == thread id
    int blockCell = blockIdx.x * BLK;
    int gid = blockCell + l;
    int b = gid / NPB;                   // uniform within a block
    int r = gid % NPB;

    // GT staging: lanes 0..31 write, all lanes read later. Same-wave DS ops
    // execute in order (write precedes read in wave program order; compiler
    // preserves order on the aliasing LDS objects) — no barrier needed.
    if (l < NGT) {
        bool u8mode = det_mask_is_u8(gt_mask);
        float4 gtb = ((const float4*)gt_bboxes)[b * NGT + l];
        float4 bx;
        bx.x = gtb.x - gtb.z * 0.5f;   // x1
        bx.y = gtb.y - gtb.w * 0.5f;   // y1
        bx.z = gtb.x + gtb.z * 0.5f;   // x2
        bx.w = gtb.y + gtb.w * 0.5f;   // y2
        s_box[l] = bx;
        float2 am;
        am.x = gtb.z * gtb.w;
        am.y = det_mask_at(gt_mask, u8mode, b * NGT + l) ? 1.0f : 0.0f;
        s_am[l] = am;
    }

    // ---- Phase 1 head: loads + decode + pbbox store ----
    int a   = r / (NH * NW);
    int rem = r % (NH * NW);
    int j   = rem / NW;
    int i   = rem % NW;

    float4 tb = ((const float4*)t_bbox)[gid];
    float confl = conf_logits[gid];
    float s0 = det_sigmoid(tb.x), s1 = det_sigmoid(tb.y);
    float s2 = det_sigmoid(tb.z), s3 = det_sigmoid(tb.w);
    float px = (s0 * 2.0f - 0.5f + (float)i) * 8.0f;
    float py = (s1 * 2.0f - 0.5f + (float)j) * 8.0f;
    float sw = s2 * 2.0f, sh = s3 * 2.0f;
    float pw = sw * sw * det_aw3(a);
    float ph = sh * sh * det_ah3(a);
    float4 pb; pb.x = px; pb.y = py; pb.z = pw; pb.w = ph;
    ((float4*)out)[gid] = pb;

    // ---- Issue phase-2 tiles 0 and 1: HBM latency hides under IoU ----
    int cl_ = l >> 2;            // local cell within 16-row tile
    int q   = l & 3;             // quad lane: scans cols [5q, 5q+5)
    const float4* g4 = (const float4*)cls_logits;
    float4* t0 = &s_cls[0][0];
    float4* t1 = &s_cls[1][0];
    __builtin_amdgcn_sched_barrier(0);
    det_issue_tile(g4, t0, (size_t)(blockCell +  0) * F4_PER_ROW, l);   // L0
    det_issue_tile(g4, t1, (size_t)(blockCell + 16) * F4_PER_ROW, l);   // L1
    __builtin_amdgcn_sched_barrier(0);

    // ---- Phase 1 tail: IoU + conf BCE + wave reduce ----
    float px1 = px - pw * 0.5f, px2 = px + pw * 0.5f;
    float py1 = py - ph * 0.5f, py2 = py + ph * 0.5f;
    float parea = pw * ph;
    float maxiou = 0.0f;
#pragma unroll
    for (int g = 0; g < NGT; g++) {
        float4 bx = s_box[g];
        float2 am = s_am[g];
        float iw = fmaxf(fminf(px2, bx.z) - fmaxf(px1, bx.x), 0.0f);
        float ih = fmaxf(fminf(py2, bx.w) - fmaxf(py1, bx.y), 0.0f);
        float inter = iw * ih;
        float uni = parea + am.x - inter;
        float iou = inter * det_rcp(uni + 1e-16f);   // continuous: rcp OK
        maxiou = fmaxf(maxiou, (am.y != 0.0f) ? iou : 0.0f);
    }

    float sconf = det_sigmoid(confl);          // kept for phase 2 via shuffle
    float lconf = det_bce(confl, maxiou);

    // Blocks 0..3 carry the 256 GT target losses (tid = bid*64 + lane).
    // Their extra VMEM only makes the phase-2 waits more conservative.
    if (blockIdx.x < 4)
        lconf += det_gt_loss(blockIdx.x * BLK + l,
                             t_bbox, cls_logits, gt_bboxes, gt_cls, gt_mask);

#pragma unroll
    for (int off = 32; off > 0; off >>= 1) lconf += __shfl_down(lconf, off, 64);
    // lane 0 holds the wave total; atomic issued at the end (after scans).

    // ---- Phase 2: 4 tiles, double-buffered DMA, counted waits, no barriers -
    // Program-order VMEM: ...older loads/stores... L0(5) L1(5) [scan+2st]
    // L2(5) [scan+2st] L3(5). vmcnt(5) => all but newest 5 retired.
#pragma unroll
    for (int it = 0; it < 4; ++it) {
        if (it < 3) DET_WAITVM(5);             // tile 'it' landed (next in flight)
        else        DET_WAITVM(0);             // last tile: drain
        const float4* tile = (it & 1) ? t1 : t0;
        const float4* rowp = tile + cl_ * F4_PER_ROW + q * 5;
        float4 v0 = rowp[0];
        float4 v1 = rowp[1];
        float4 v2 = rowp[2];
        float4 v3 = rowp[3];
        float4 v4 = rowp[4];
        // ds_reads retire before any later-issued DMA overwrites the buffer:
        // the re-issue below targets the SAME buffer only two tiles later,
        // and the intervening vmcnt waits order DMA-writes after these reads.
        if (it < 2) {
            __builtin_amdgcn_sched_barrier(0);
            asm volatile("s_waitcnt lgkmcnt(0)" ::: "memory"); // reads in regs
            __builtin_amdgcn_sched_barrier(0);
            det_issue_tile(g4, (float4*)tile,
                           (size_t)(blockCell + (it + 2) * 16) * F4_PER_ROW, l);
        }

        float mx = -1e30f;
        int mi = 0;
        int cb = q * 20;                       // first class of this lane
        { int c = cb;
          if (v0.x > mx) { mx = v0.x; mi = c + 0; }
          if (v0.y > mx) { mx = v0.y; mi = c + 1; }
          if (v0.z > mx) { mx = v0.z; mi = c + 2; }
          if (v0.w > mx) { mx = v0.w; mi = c + 3; } }
        { int c = cb + 4;
          if (v1.x > mx) { mx = v1.x; mi = c + 0; }
          if (v1.y > mx) { mx = v1.y; mi = c + 1; }
          if (v1.z > mx) { mx = v1.z; mi = c + 2; }
          if (v1.w > mx) { mx = v1.w; mi = c + 3; } }
        { int c = cb + 8;
          if (v2.x > mx) { mx = v2.x; mi = c + 0; }
          if (v2.y > mx) { mx = v2.y; mi = c + 1; }
          if (v2.z > mx) { mx = v2.z; mi = c + 2; }
          if (v2.w > mx) { mx = v2.w; mi = c + 3; } }
        { int c = cb + 12;
          if (v3.x > mx) { mx = v3.x; mi = c + 0; }
          if (v3.y > mx) { mx = v3.y; mi = c + 1; }
          if (v3.z > mx) { mx = v3.z; mi = c + 2; }
          if (v3.w > mx) { mx = v3.w; mi = c + 3; } }
        { int c = cb + 16;
          if (v4.x > mx) { mx = v4.x; mi = c + 0; }
          if (v4.y > mx) { mx = v4.y; mi = c + 1; }
          if (v4.z > mx) { mx = v4.z; mi = c + 2; }
          if (v4.w > mx) { mx = v4.w; mi = c + 3; } }

        // quad reduce: lexicographic (value, lower index) == jnp first-max
#pragma unroll
        for (int s = 1; s < 4; s <<= 1) {
            float ov = __shfl_xor(mx, s, 64);
            int   oi = __shfl_xor(mi, s, 64);
            if (ov > mx || (ov == mx && oi < mi)) { mx = ov; mi = oi; }
        }
        // sigmoid(conf) of this tile's cell lives in lane it*16+cl_ (phase 1)
        float sc = __shfl(sconf, it * 16 + cl_, 64);
        if (q == 0) {                          // 16 lanes, 64B contiguous
            int cellg = blockCell + it * 16 + cl_;
            out[OFF_CLSIDX + cellg] = (float)mi;
            out[OFF_SCORE  + cellg] = sc * det_sigmoid(mx);
        }
    }

    // ---- Epilogue: wave total -> spread atomic slot ------------------------
    if (l == 0)
        atomicAdd(&g_acc[(blockIdx.x & 7) * 16], lconf);
}

// ---------------- Finalize: sum slots, write loss, reset -------------------
__global__ void det_fin_k(float* __restrict__ out) {
    float tot = 0.0f;
#pragma unroll
    for (int s = 0; s < 8; ++s) { tot += g_acc[s * 16]; g_acc[s * 16] = 0.0f; }
    out[OFF_LOSS] = tot * (1.0f / NB);
}

extern "C" void kernel_launch(void* const* d_in, const int* in_sizes, int n_in,
                              void* d_out, int out_size, void* d_ws, size_t ws_size,
                              hipStream_t stream) {
    (void)in_sizes; (void)n_in; (void)out_size; (void)d_ws; (void)ws_size;
    const float* t_bbox      = (const float*)d_in[0];
    const float* conf_logits = (const float*)d_in[1];
    const float* cls_logits  = (const float*)d_in[2];
    const float* gt_bboxes   = (const float*)d_in[3];
    const int*   gt_cls      = (const int*)d_in[4];
    const void*  gt_mask     = (const void*)d_in[5];  // layout auto-detected
    float* out = (float*)d_out;                       // float32 per reference

    det_all_k<<<NBLK, BLK, 0, stream>>>(t_bbox, conf_logits, cls_logits,
                                        gt_bboxes, gt_cls, gt_mask, out);
    det_fin_k<<<1, 1, 0, stream>>>(out);
}